// Round 8
// baseline (103.763 us; speedup 1.0000x reference)
//
#include <hip/hip_runtime.h>

// Performer causal linear attention — 2-dispatch bf16-MFMA pipeline, L=64.
// B=4, S=2048, D=128; chunks of L=64 (128 chunks total, 32/batch).
//  phikv (256 blk x 512 thr): phi = scale*exp(W@x) via MFMA; K-blocks also
//         emit per-chunk KVT[e][d] (bf16, layout [b][e][c][d]) + N[d] (fp32).
//  out (512 blk = b x 32c x 4 e-quarters): each block computes its own
//         exclusive M/N prefix from KVT/N32 (L2-resident, fp32 acc), then
//         P=QK^T (masked); out = P@V + Q@M ; fp32 denominators.
//  (Round-5 lesson: software grid barriers cost ~100us on 8 non-coherent
//   XCD L2s; round-8 lesson target: the prefix DISPATCH itself is pure
//   overhead — triangular L2 re-reads are cheaper.)
typedef float v4 __attribute__((ext_vector_type(4)));
typedef short s8v __attribute__((ext_vector_type(8)));   // bf16x8 fragment
typedef float f4v __attribute__((ext_vector_type(4)));   // mfma C/D
typedef unsigned short u16;
typedef u16 us2 __attribute__((ext_vector_type(2)));
typedef u16 us4 __attribute__((ext_vector_type(4)));
typedef u16 us8 __attribute__((ext_vector_type(8)));

// workspace layout (float units)
#define OFF_PHIKB 0            // bf16 [8192][128]          (524288 f)
#define OFF_PHIQB 524288       // bf16 [8192][128]          (524288 f)
#define OFF_KVTB  1048576      // bf16 [4][128][32][128]    (1048576 f)
#define OFF_N32   2097152      // fp32 [4][32][128]         (16384 f)
// total 2113536 floats = 8.5 MB

__device__ inline u16 f2bf(float f) {
  union { float f; unsigned u; } v; v.f = f;
  unsigned r = v.u + 0x7fffu + ((v.u >> 16) & 1u);
  return (u16)(r >> 16);
}
__device__ inline float bf2f(u16 h) {
  union { unsigned u; float f; } v; v.u = ((unsigned)h) << 16; return v.f;
}

// ---------------------------------------------------------------------------
// Kernel 1: fused phi (+ per-chunk KV/N for the K tensor).  L=64 chunk/block.
// Grid (128, 2): x = 64-row slab (=1 chunk), y = 0:K(+kv) / 1:Q.  512 thr.
// ---------------------------------------------------------------------------
__global__ __launch_bounds__(512) void phikv_kernel(
    const float* __restrict__ K, const float* __restrict__ Q,
    const float* __restrict__ V, const float* __restrict__ W,
    u16* __restrict__ phiKb, u16* __restrict__ phiQb,
    u16* __restrict__ KVTb, float* __restrict__ N32) {
  // phase A: Xb[64][136] @ 0, Wb[128][136] @ 8704   (u16 units)
  // phase B: Pb[64][136] @ 0, KdT[128][72] @ 8704, Vt[128][72] @ 17920
  __shared__ __align__(16) u16 smem[27136];
  __shared__ float srowsq[64];
  __shared__ float scl[64];
  u16* Xb = smem;
  u16* Wb = smem + 8704;
  u16* Pb = smem;
  u16* KdT = smem + 8704;
  u16* Vt = smem + 17920;

  const int tid = threadIdx.x;
  const bool isK = (blockIdx.y == 0);
  const float* X = isK ? K : Q;
  u16* outPhi = isK ? phiKb : phiQb;
  const int row0 = blockIdx.x * 64;
  const int wv = tid >> 6;   // 0..7
  const int lane = tid & 63;
  const int q = lane >> 4;
  const int ln = lane & 15;

  // ---- prefetch V row-pairs (K-blocks): enables conflict-free transpose ----
  v4 vpa[2], vpb[2];
  if (isK) {
#pragma unroll
    for (int k = 0; k < 2; k++) {
      int j = tid + k * 512;
      int s0 = (j & 31) * 2;
      int e4 = (j >> 5) * 4;  // 0..124
      vpa[k] = *(const v4*)&V[(size_t)(row0 + s0) * 128 + e4];
      vpb[k] = *(const v4*)&V[(size_t)(row0 + s0 + 1) * 128 + e4];
    }
  }

  // ---- stage X -> bf16 Xb + per-row sumsq (fp32, shuffle-reduced) ----
#pragma unroll
  for (int k = 0; k < 4; k++) {
    int j = tid + k * 512;
    int r = j >> 5;
    int c4 = (j & 31) * 4;
    v4 x = *(const v4*)&X[(size_t)(row0 + r) * 128 + c4];
    us4 xb;
    float p = 0.f;
#pragma unroll
    for (int i = 0; i < 4; i++) { xb[i] = f2bf(x[i]); p += x[i] * x[i]; }
    *(us4*)&Xb[r * 136 + c4] = xb;
    p += __shfl_down(p, 16, 32);
    p += __shfl_down(p, 8, 32);
    p += __shfl_down(p, 4, 32);
    p += __shfl_down(p, 2, 32);
    p += __shfl_down(p, 1, 32);
    if ((tid & 31) == 0) srowsq[r] = p;
  }
  // ---- stage W -> bf16 Wb ----
#pragma unroll
  for (int k = 0; k < 8; k++) {
    int j = tid + k * 512;
    int r = j >> 5;
    int c4 = (j & 31) * 4;
    v4 w = *(const v4*)&W[(size_t)r * 128 + c4];
    us4 wb;
#pragma unroll
    for (int i = 0; i < 4; i++) wb[i] = f2bf(w[i]);
    *(us4*)&Wb[r * 136 + c4] = wb;
  }
  __syncthreads();
  if (tid < 64)
    scl[tid] = 0.08838834764831845f * __expf(-0.5f * sqrtf(srowsq[tid]));

  // ---- phi MFMA: wave -> row-tile tr=wv>>1, col-tiles (wv&1)*4.. ----
  const int tr = wv >> 1;
  const int cb = (wv & 1) * 4;
  f4v acc[4];
#pragma unroll
  for (int i = 0; i < 4; i++) acc[i] = (f4v){0.f, 0.f, 0.f, 0.f};
#pragma unroll
  for (int ks = 0; ks < 4; ks++) {
    s8v a = *(const s8v*)&Xb[(tr * 16 + ln) * 136 + ks * 32 + q * 8];
#pragma unroll
    for (int i = 0; i < 4; i++) {
      s8v bb = *(const s8v*)&Wb[((cb + i) * 16 + ln) * 136 + ks * 32 + q * 8];
      acc[i] = __builtin_amdgcn_mfma_f32_16x16x32_bf16(a, bb, acc[i], 0, 0, 0);
    }
  }
  __syncthreads();  // Xb/Wb reads done; scl ready

  // ---- epilogue: phi -> Pb (row-major) + KdT (transposed, K-blocks) ----
#pragma unroll
  for (int i = 0; i < 4; i++) {
    const int ct = cb + i;
    us4 col;
#pragma unroll
    for (int r = 0; r < 4; r++) {
      int row = tr * 16 + q * 4 + r;
      u16 hv = f2bf(scl[row] * __expf(acc[i][r]));
      Pb[row * 136 + ct * 16 + ln] = hv;
      col[r] = hv;
    }
    if (isK) *(us4*)&KdT[(ct * 16 + ln) * 72 + tr * 16 + q * 4] = col;
  }
  // ---- Vt from prefetch regs: us2 row-pair stores, conflict-free ----
  if (isK) {
#pragma unroll
    for (int k = 0; k < 2; k++) {
      int j = tid + k * 512;
      int s0 = (j & 31) * 2;
      int e4 = (j >> 5) * 4;
#pragma unroll
      for (int i = 0; i < 4; i++) {
        us2 w2 = {f2bf(vpa[k][i]), f2bf(vpb[k][i])};
        *(us2*)&Vt[(e4 + i) * 72 + s0] = w2;
      }
    }
  }
  __syncthreads();

  // ---- phi -> global (coalesced us8) ----
#pragma unroll
  for (int k = 0; k < 2; k++) {
    int j = tid + k * 512;
    int r = j >> 4;
    int d8 = (j & 15) * 8;
    *(us8*)&outPhi[(size_t)(row0 + r) * 128 + d8] = *(const us8*)&Pb[r * 136 + d8];
  }
  if (!isK) return;

  const int b = row0 >> 11;
  const int c = (row0 >> 6) & 31;  // this block's chunk

  // ---- N sums over 64 rows ----
  if (tid < 128) {
    float ns = 0.f;
#pragma unroll
    for (int s = 0; s < 64; s++) ns += bf2f(KdT[tid * 72 + s]);
    N32[(size_t)(b * 32 + c) * 128 + tid] = ns;
  }

  // ---- kv MFMA: KVT[e][d] = sum_{s<64} V[s][e]*phiK[s][d] ----
  {
    const int et = wv;  // 8 e-tiles / 8 waves
    s8v a0 = *(const s8v*)&Vt[(et * 16 + ln) * 72 + q * 8];
    s8v a1 = *(const s8v*)&Vt[(et * 16 + ln) * 72 + 32 + q * 8];
    f4v ac[8];
#pragma unroll
    for (int dt = 0; dt < 8; dt++) ac[dt] = (f4v){0.f, 0.f, 0.f, 0.f};
#pragma unroll
    for (int dt = 0; dt < 8; dt++) {
      s8v b0 = *(const s8v*)&KdT[(dt * 16 + ln) * 72 + q * 8];
      ac[dt] = __builtin_amdgcn_mfma_f32_16x16x32_bf16(a0, b0, ac[dt], 0, 0, 0);
      s8v b1 = *(const s8v*)&KdT[(dt * 16 + ln) * 72 + 32 + q * 8];
      ac[dt] = __builtin_amdgcn_mfma_f32_16x16x32_bf16(a1, b1, ac[dt], 0, 0, 0);
    }
#pragma unroll
    for (int dt = 0; dt < 8; dt++)
#pragma unroll
      for (int r = 0; r < 4; r++) {
        int e = et * 16 + q * 4 + r;
        int d = dt * 16 + ln;
        KVTb[((size_t)(b * 128 + e) * 32 + c) * 128 + d] = f2bf(ac[dt][r]);
      }
  }
}

// ---------------------------------------------------------------------------
// Kernel 2: outputs with in-block M/N prefix.  Block = (b, chunk c, quarter h).
// Blocks mapped to DESCENDING c so triangular scan work dispatches first.
// Grid 512, ~57 KB LDS -> 2 blocks/CU.
// ---------------------------------------------------------------------------
__global__ __launch_bounds__(256) void out_kernel(
    const u16* __restrict__ phiKb, const u16* __restrict__ phiQb,
    const float* __restrict__ V, const u16* __restrict__ KVTb,
    const float* __restrict__ N32, float* __restrict__ out) {
  __shared__ __align__(16) u16 Qs[64 * 136];  // [t][d]
  __shared__ __align__(16) u16 Ks[64 * 136];  // [s][d]
  __shared__ __align__(16) u16 Ms[32 * 136];  // M^T rows of this quarter
  __shared__ __align__(16) u16 Vt[32 * 72];   // [e][s]
  __shared__ __align__(16) u16 Ps[64 * 72];   // [t][s], masked
  __shared__ float Ns[128];
  __shared__ float rs[64];

  const int tid = threadIdx.x;
  const int id = blockIdx.x;
  const int h = id & 3;
  const int c = 31 - ((id >> 2) & 31);  // descending chunk order
  const int b = id >> 7;
  const int srow0 = b * 2048 + c * 64;
  const int ecol0 = h * 32;
  const int wv = tid >> 6;
  const int lane = tid & 63;
  const int q = lane >> 4;
  const int ln = lane & 15;

  // ---- V prefetch (row-pairs of this 32-col quarter) ----
  const int vs0 = (tid & 31) * 2;
  const int ve4 = (tid >> 5) * 4;  // 0..28
  v4 va = *(const v4*)&V[(size_t)(srow0 + vs0) * 128 + ecol0 + ve4];
  v4 vb = *(const v4*)&V[(size_t)(srow0 + vs0 + 1) * 128 + ecol0 + ve4];

  // ---- stage Qs, Ks (64 x 128 bf16 each) ----
#pragma unroll
  for (int k = 0; k < 4; k++) {
    int j = tid + k * 256;  // 0..1023
    int t = j >> 4;
    int d8 = (j & 15) * 8;
    *(us8*)&Qs[t * 136 + d8] = *(const us8*)&phiQb[(size_t)(srow0 + t) * 128 + d8];
    *(us8*)&Ks[t * 136 + d8] = *(const us8*)&phiKb[(size_t)(srow0 + t) * 128 + d8];
  }

  // ---- exclusive M-prefix over chunks < c (KVT is L2-resident; fp32 acc).
  //      thread -> e rows {se, se+16} x d8 group; loads independent of acc.
  {
    const int se = tid >> 4;          // 0..15
    const int sd8 = (tid & 15) * 8;
    const u16* src0 =
        &KVTb[((size_t)(b * 128 + ecol0 + se) * 32) * 128 + sd8];
    const u16* src1 =
        &KVTb[((size_t)(b * 128 + ecol0 + 16 + se) * 32) * 128 + sd8];
    float m0[8], m1[8];
#pragma unroll
    for (int i = 0; i < 8; i++) { m0[i] = 0.f; m1[i] = 0.f; }
    for (int cp = 0; cp < c; cp++) {
      us8 k0 = *(const us8*)&src0[cp * 128];
      us8 k1 = *(const us8*)&src1[cp * 128];
#pragma unroll
      for (int i = 0; i < 8; i++) {
        m0[i] += bf2f(k0[i]);
        m1[i] += bf2f(k1[i]);
      }
    }
    us8 w0, w1;
#pragma unroll
    for (int i = 0; i < 8; i++) { w0[i] = f2bf(m0[i]); w1[i] = f2bf(m1[i]); }
    *(us8*)&Ms[se * 136 + sd8] = w0;
    *(us8*)&Ms[(16 + se) * 136 + sd8] = w1;
  }
  // ---- exclusive N-prefix ----
  if (tid < 128) {
    float na = 0.f;
    for (int cp = 0; cp < c; cp++)
      na += N32[(size_t)(b * 32 + cp) * 128 + tid];
    Ns[tid] = na;
  }
  // ---- Vt: us2 row-pair stores, conflict-free ----
#pragma unroll
  for (int i = 0; i < 4; i++) {
    us2 w2 = {f2bf(va[i]), f2bf(vb[i])};
    *(us2*)&Vt[(ve4 + i) * 72 + vs0] = w2;
  }
  __syncthreads();

  // ---- P = Q.K^T (wave = row-tile tr=wv; tc 0..3, causal) ----
  {
    const int tr = wv;
    for (int tc = 0; tc < 4; tc++) {  // wave-uniform bound
      f4v acc = {0.f, 0.f, 0.f, 0.f};
      if (tc <= tr) {
#pragma unroll
        for (int ks = 0; ks < 4; ks++) {
          s8v a = *(const s8v*)&Qs[(tr * 16 + ln) * 136 + ks * 32 + q * 8];
          s8v bb = *(const s8v*)&Ks[(tc * 16 + ln) * 136 + ks * 32 + q * 8];
          acc = __builtin_amdgcn_mfma_f32_16x16x32_bf16(a, bb, acc, 0, 0, 0);
        }
      }
      const int s_g = tc * 16 + ln;
#pragma unroll
      for (int r = 0; r < 4; r++) {
        int t_g = tr * 16 + q * 4 + r;
        Ps[t_g * 72 + s_g] = f2bf(s_g <= t_g ? acc[r] : 0.f);
      }
    }
  }
  __syncthreads();

  // ---- denominators: rs[t] = rowsum(P) + Q[t,:].Ns ----
  {
    const int t = tid >> 2;
    const int p4 = tid & 3;
    float rsl = 0.f;
#pragma unroll
    for (int s = p4; s < 64; s += 4) rsl += bf2f(Ps[t * 72 + s]);
#pragma unroll
    for (int d = p4; d < 128; d += 4) rsl += bf2f(Qs[t * 136 + d]) * Ns[d];
    rsl += __shfl_down(rsl, 2, 4);
    rsl += __shfl_down(rsl, 1, 4);
    if (p4 == 0) rs[t] = rsl;
  }

  // ---- out = P@V + Q@M (wave: et = wv&1; tr in {wv>>1, wv>>1 + 2}) ----
  const int et = wv & 1;
  f4v acc2[2];
#pragma unroll
  for (int i = 0; i < 2; i++) acc2[i] = (f4v){0.f, 0.f, 0.f, 0.f};
#pragma unroll
  for (int i = 0; i < 2; i++) {
    const int tr2 = (wv >> 1) + 2 * i;
#pragma unroll
    for (int ks2 = 0; ks2 < 2; ks2++) {
      s8v a_p = *(const s8v*)&Ps[(tr2 * 16 + ln) * 72 + ks2 * 32 + q * 8];
      s8v b_v = *(const s8v*)&Vt[(et * 16 + ln) * 72 + ks2 * 32 + q * 8];
      acc2[i] = __builtin_amdgcn_mfma_f32_16x16x32_bf16(a_p, b_v, acc2[i], 0, 0, 0);
    }
#pragma unroll
    for (int ks = 0; ks < 4; ks++) {
      s8v a_q = *(const s8v*)&Qs[(tr2 * 16 + ln) * 136 + ks * 32 + q * 8];
      s8v b_m = *(const s8v*)&Ms[(et * 16 + ln) * 136 + ks * 32 + q * 8];
      acc2[i] = __builtin_amdgcn_mfma_f32_16x16x32_bf16(a_q, b_m, acc2[i], 0, 0, 0);
    }
  }
  __syncthreads();  // rs ready

  // ---- epilogue ----
#pragma unroll
  for (int i = 0; i < 2; i++) {
    const int tr2 = (wv >> 1) + 2 * i;
#pragma unroll
    for (int r = 0; r < 4; r++) {
      int t_g = tr2 * 16 + q * 4 + r;
      float rv = rs[t_g];
      float den = rv + (rv > 0.f ? 1e-6f : (rv < 0.f ? -1e-6f : 0.f));
      out[(size_t)(srow0 + t_g) * 128 + ecol0 + et * 16 + ln] =
          acc2[i][r] / den;
    }
  }
}

// ---------------------------------------------------------------------------
extern "C" void kernel_launch(void* const* d_in, const int* in_sizes, int n_in,
                              void* d_out, int out_size, void* d_ws,
                              size_t ws_size, hipStream_t stream) {
  (void)in_sizes; (void)n_in; (void)out_size; (void)ws_size;
  const float* K = (const float*)d_in[0];
  const float* Q = (const float*)d_in[1];
  const float* V = (const float*)d_in[2];
  const float* W = (const float*)d_in[6];
  float* out = (float*)d_out;
  float* ws = (float*)d_ws;

  u16* phiKb = (u16*)(ws + OFF_PHIKB);
  u16* phiQb = (u16*)(ws + OFF_PHIQB);
  u16* KVTb = (u16*)(ws + OFF_KVTB);
  float* N32 = ws + OFF_N32;

  phikv_kernel<<<dim3(128, 2), 512, 0, stream>>>(K, Q, V, W, phiKb, phiQb,
                                                 KVTb, N32);
  out_kernel<<<512, 256, 0, stream>>>(phiKb, phiQb, V, KVTb, N32, out);
}

// Round 9
// 93.884 us; speedup vs baseline: 1.1052x; 1.1052x over previous
//
#include <hip/hip_runtime.h>

// Performer causal linear attention — 3-dispatch bf16-MFMA pipeline, L=64.
// B=4, S=2048, D=128; chunks of L=64 (128 chunks total, 32/batch).
//  phikv (256 blk x 512 thr): phi = scale*exp(W@x) via MFMA; K-blocks also
//         emit per-chunk KVT[e][d] (bf16) + N[d] (fp32).
//  prefix (65 blk): exclusive scan over 32 chunks -> bf16 PM (M^T) + fp32 PN.
//         Fully unrolled load/scan/store so all 32 loads pipeline.
//  out (512 blk = b x 32c x 4 e-quarters, 2 blk/CU): P=QK^T (masked);
//         out = P@V + Q@M ; fp32 denominators.
// (R5 lesson: grid barriers cost ~100us across 8 non-coherent XCD L2s.
//  R8 lesson: in-block triangular prefix puts a serial scan on the longest
//  co-resident block -> tail latency; the dedicated dispatch is cheaper.)
typedef float v4 __attribute__((ext_vector_type(4)));
typedef float v2 __attribute__((ext_vector_type(2)));
typedef short s8v __attribute__((ext_vector_type(8)));   // bf16x8 fragment
typedef float f4v __attribute__((ext_vector_type(4)));   // mfma C/D
typedef unsigned short u16;
typedef u16 us2 __attribute__((ext_vector_type(2)));
typedef u16 us4 __attribute__((ext_vector_type(4)));
typedef u16 us8 __attribute__((ext_vector_type(8)));

// workspace layout (float units)
#define OFF_PHIKB 0            // bf16 [8192][128]          (524288 f)
#define OFF_PHIQB 524288       // bf16 [8192][128]          (524288 f)
#define OFF_KVTB  1048576      // bf16 [4][128][32][128]    (1048576 f)
#define OFF_PMB   2097152      // bf16 [4][128][32][128]    (1048576 f)
#define OFF_N32   3145728      // fp32 [4][32][128]         (16384 f)
#define OFF_PN    3162112      // fp32 [4][32][128]         (16384 f)
// total 3178496 floats = 12.7 MB

__device__ inline u16 f2bf(float f) {
  union { float f; unsigned u; } v; v.f = f;
  unsigned r = v.u + 0x7fffu + ((v.u >> 16) & 1u);
  return (u16)(r >> 16);
}
__device__ inline float bf2f(u16 h) {
  union { unsigned u; float f; } v; v.u = ((unsigned)h) << 16; return v.f;
}

// ---------------------------------------------------------------------------
// Kernel 1: fused phi (+ per-chunk KV/N for the K tensor).  L=64 chunk/block.
// Grid (128, 2): x = 64-row slab (=1 chunk), y = 0:K(+kv) / 1:Q.  512 thr.
// ---------------------------------------------------------------------------
__global__ __launch_bounds__(512) void phikv_kernel(
    const float* __restrict__ K, const float* __restrict__ Q,
    const float* __restrict__ V, const float* __restrict__ W,
    u16* __restrict__ phiKb, u16* __restrict__ phiQb,
    u16* __restrict__ KVTb, float* __restrict__ N32) {
  // phase A: Xb[64][136] @ 0, Wb[128][136] @ 8704   (u16 units)
  // phase B: Pb[64][136] @ 0, KdT[128][72] @ 8704, Vt[128][72] @ 17920
  __shared__ __align__(16) u16 smem[27136];
  __shared__ float srowsq[64];
  __shared__ float scl[64];
  u16* Xb = smem;
  u16* Wb = smem + 8704;
  u16* Pb = smem;
  u16* KdT = smem + 8704;
  u16* Vt = smem + 17920;

  const int tid = threadIdx.x;
  const bool isK = (blockIdx.y == 0);
  const float* X = isK ? K : Q;
  u16* outPhi = isK ? phiKb : phiQb;
  const int row0 = blockIdx.x * 64;
  const int wv = tid >> 6;   // 0..7
  const int lane = tid & 63;
  const int q = lane >> 4;
  const int ln = lane & 15;

  // ---- prefetch V row-pairs (K-blocks): enables conflict-free transpose ----
  v4 vpa[2], vpb[2];
  if (isK) {
#pragma unroll
    for (int k = 0; k < 2; k++) {
      int j = tid + k * 512;
      int s0 = (j & 31) * 2;
      int e4 = (j >> 5) * 4;  // 0..124
      vpa[k] = *(const v4*)&V[(size_t)(row0 + s0) * 128 + e4];
      vpb[k] = *(const v4*)&V[(size_t)(row0 + s0 + 1) * 128 + e4];
    }
  }

  // ---- stage X -> bf16 Xb + per-row sumsq (fp32, shuffle-reduced) ----
#pragma unroll
  for (int k = 0; k < 4; k++) {
    int j = tid + k * 512;
    int r = j >> 5;
    int c4 = (j & 31) * 4;
    v4 x = *(const v4*)&X[(size_t)(row0 + r) * 128 + c4];
    us4 xb;
    float p = 0.f;
#pragma unroll
    for (int i = 0; i < 4; i++) { xb[i] = f2bf(x[i]); p += x[i] * x[i]; }
    *(us4*)&Xb[r * 136 + c4] = xb;
    p += __shfl_down(p, 16, 32);
    p += __shfl_down(p, 8, 32);
    p += __shfl_down(p, 4, 32);
    p += __shfl_down(p, 2, 32);
    p += __shfl_down(p, 1, 32);
    if ((tid & 31) == 0) srowsq[r] = p;
  }
  // ---- stage W -> bf16 Wb ----
#pragma unroll
  for (int k = 0; k < 8; k++) {
    int j = tid + k * 512;
    int r = j >> 5;
    int c4 = (j & 31) * 4;
    v4 w = *(const v4*)&W[(size_t)r * 128 + c4];
    us4 wb;
#pragma unroll
    for (int i = 0; i < 4; i++) wb[i] = f2bf(w[i]);
    *(us4*)&Wb[r * 136 + c4] = wb;
  }
  __syncthreads();
  if (tid < 64)
    scl[tid] = 0.08838834764831845f * __expf(-0.5f * sqrtf(srowsq[tid]));

  // ---- phi MFMA: wave -> row-tile tr=wv>>1, col-tiles (wv&1)*4.. ----
  const int tr = wv >> 1;
  const int cb = (wv & 1) * 4;
  f4v acc[4];
#pragma unroll
  for (int i = 0; i < 4; i++) acc[i] = (f4v){0.f, 0.f, 0.f, 0.f};
#pragma unroll
  for (int ks = 0; ks < 4; ks++) {
    s8v a = *(const s8v*)&Xb[(tr * 16 + ln) * 136 + ks * 32 + q * 8];
#pragma unroll
    for (int i = 0; i < 4; i++) {
      s8v bb = *(const s8v*)&Wb[((cb + i) * 16 + ln) * 136 + ks * 32 + q * 8];
      acc[i] = __builtin_amdgcn_mfma_f32_16x16x32_bf16(a, bb, acc[i], 0, 0, 0);
    }
  }
  __syncthreads();  // Xb/Wb reads done; scl ready

  // ---- epilogue: phi -> Pb (row-major) + KdT (transposed, K-blocks) ----
#pragma unroll
  for (int i = 0; i < 4; i++) {
    const int ct = cb + i;
    us4 col;
#pragma unroll
    for (int r = 0; r < 4; r++) {
      int row = tr * 16 + q * 4 + r;
      u16 hv = f2bf(scl[row] * __expf(acc[i][r]));
      Pb[row * 136 + ct * 16 + ln] = hv;
      col[r] = hv;
    }
    if (isK) *(us4*)&KdT[(ct * 16 + ln) * 72 + tr * 16 + q * 4] = col;
  }
  // ---- Vt from prefetch regs: us2 row-pair stores, conflict-free ----
  if (isK) {
#pragma unroll
    for (int k = 0; k < 2; k++) {
      int j = tid + k * 512;
      int s0 = (j & 31) * 2;
      int e4 = (j >> 5) * 4;
#pragma unroll
      for (int i = 0; i < 4; i++) {
        us2 w2 = {f2bf(vpa[k][i]), f2bf(vpb[k][i])};
        *(us2*)&Vt[(e4 + i) * 72 + s0] = w2;
      }
    }
  }
  __syncthreads();

  // ---- phi -> global (coalesced us8) ----
#pragma unroll
  for (int k = 0; k < 2; k++) {
    int j = tid + k * 512;
    int r = j >> 4;
    int d8 = (j & 15) * 8;
    *(us8*)&outPhi[(size_t)(row0 + r) * 128 + d8] = *(const us8*)&Pb[r * 136 + d8];
  }
  if (!isK) return;

  const int b = row0 >> 11;
  const int c = (row0 >> 6) & 31;  // this block's chunk

  // ---- N sums over 64 rows ----
  if (tid < 128) {
    float ns = 0.f;
#pragma unroll
    for (int s = 0; s < 64; s++) ns += bf2f(KdT[tid * 72 + s]);
    N32[(size_t)(b * 32 + c) * 128 + tid] = ns;
  }

  // ---- kv MFMA: KVT[e][d] = sum_{s<64} V[s][e]*phiK[s][d] ----
  {
    const int et = wv;  // 8 e-tiles / 8 waves
    s8v a0 = *(const s8v*)&Vt[(et * 16 + ln) * 72 + q * 8];
    s8v a1 = *(const s8v*)&Vt[(et * 16 + ln) * 72 + 32 + q * 8];
    f4v ac[8];
#pragma unroll
    for (int dt = 0; dt < 8; dt++) ac[dt] = (f4v){0.f, 0.f, 0.f, 0.f};
#pragma unroll
    for (int dt = 0; dt < 8; dt++) {
      s8v b0 = *(const s8v*)&KdT[(dt * 16 + ln) * 72 + q * 8];
      ac[dt] = __builtin_amdgcn_mfma_f32_16x16x32_bf16(a0, b0, ac[dt], 0, 0, 0);
      s8v b1 = *(const s8v*)&KdT[(dt * 16 + ln) * 72 + 32 + q * 8];
      ac[dt] = __builtin_amdgcn_mfma_f32_16x16x32_bf16(a1, b1, ac[dt], 0, 0, 0);
    }
#pragma unroll
    for (int dt = 0; dt < 8; dt++)
#pragma unroll
      for (int r = 0; r < 4; r++) {
        int e = et * 16 + q * 4 + r;
        int d = dt * 16 + ln;
        KVTb[((size_t)(b * 128 + e) * 32 + c) * 128 + d] = f2bf(ac[dt][r]);
      }
  }
}

// ---------------------------------------------------------------------------
// Kernel 2: exclusive prefix over 32 chunks.  Layout [b][e][c][d].
// Blocks 0..63: 8 M^T rows each (32 thr/row, us4/thread); block 64: N.
// Load-all / scan-in-regs / store-all so all 32 loads are in flight at once.
// ---------------------------------------------------------------------------
__global__ __launch_bounds__(256) void prefix_kernel(
    const u16* __restrict__ KVTb, const float* __restrict__ N32,
    u16* __restrict__ PMb, float* __restrict__ PN) {
  const int tid = threadIdx.x;
  const int bid = blockIdx.x;
  if (bid < 64) {
    const int r = bid * 8 + (tid >> 5);  // 0..511 = b*128+e
    const int d4 = (tid & 31) * 4;
    const size_t base = (size_t)r * (32 * 128);
    us4 kv[32];
#pragma unroll
    for (int c = 0; c < 32; c++) kv[c] = *(const us4*)&KVTb[base + c * 128 + d4];
    us4 st[32];
    float acc[4] = {0.f, 0.f, 0.f, 0.f};
#pragma unroll
    for (int c = 0; c < 32; c++) {
#pragma unroll
      for (int i = 0; i < 4; i++) {
        st[c][i] = f2bf(acc[i]);
        acc[i] += bf2f(kv[c][i]);
      }
    }
#pragma unroll
    for (int c = 0; c < 32; c++) *(us4*)&PMb[base + c * 128 + d4] = st[c];
  } else {
    const int b = tid >> 6;
    const int d2 = (tid & 63) * 2;
    v2 nv[32];
#pragma unroll
    for (int c = 0; c < 32; c++)
      nv[c] = *(const v2*)&N32[(size_t)(b * 32 + c) * 128 + d2];
    float a0 = 0.f, a1 = 0.f;
#pragma unroll
    for (int c = 0; c < 32; c++) {
      *(v2*)&PN[(size_t)(b * 32 + c) * 128 + d2] = (v2){a0, a1};
      a0 += nv[c][0];
      a1 += nv[c][1];
    }
  }
}

// ---------------------------------------------------------------------------
// Kernel 3: outputs.  Block = (b, chunk c of 64, e-quarter h of 32 cols).
// Grid 512, ~57 KB LDS -> 2 blocks/CU.
// ---------------------------------------------------------------------------
__global__ __launch_bounds__(256) void out_kernel(
    const u16* __restrict__ phiKb, const u16* __restrict__ phiQb,
    const float* __restrict__ V, const u16* __restrict__ PMb,
    const float* __restrict__ PN, float* __restrict__ out) {
  __shared__ __align__(16) u16 Qs[64 * 136];  // [t][d]
  __shared__ __align__(16) u16 Ks[64 * 136];  // [s][d]
  __shared__ __align__(16) u16 Ms[32 * 136];  // M^T rows of this quarter
  __shared__ __align__(16) u16 Vt[32 * 72];   // [e][s]
  __shared__ __align__(16) u16 Ps[64 * 72];   // [t][s], masked
  __shared__ float Ns[128];
  __shared__ float rs[64];

  const int tid = threadIdx.x;
  const int id = blockIdx.x;
  const int h = id & 3;
  const int c = (id >> 2) & 31;
  const int b = id >> 7;
  const int srow0 = b * 2048 + c * 64;
  const int ecol0 = h * 32;
  const int wv = tid >> 6;
  const int lane = tid & 63;
  const int q = lane >> 4;
  const int ln = lane & 15;

  // ---- V prefetch (row-pairs of this 32-col quarter) ----
  const int vs0 = (tid & 31) * 2;
  const int ve4 = (tid >> 5) * 4;  // 0..28
  v4 va = *(const v4*)&V[(size_t)(srow0 + vs0) * 128 + ecol0 + ve4];
  v4 vb = *(const v4*)&V[(size_t)(srow0 + vs0 + 1) * 128 + ecol0 + ve4];

  // ---- stage Qs, Ks (64 x 128 bf16 each) ----
#pragma unroll
  for (int k = 0; k < 4; k++) {
    int j = tid + k * 256;  // 0..1023
    int t = j >> 4;
    int d8 = (j & 15) * 8;
    *(us8*)&Qs[t * 136 + d8] = *(const us8*)&phiQb[(size_t)(srow0 + t) * 128 + d8];
    *(us8*)&Ks[t * 136 + d8] = *(const us8*)&phiKb[(size_t)(srow0 + t) * 128 + d8];
  }
  // ---- stage Ms (32 e-rows) + Ns ----
#pragma unroll
  for (int k = 0; k < 2; k++) {
    int j = tid + k * 256;  // 0..511
    int e = j >> 4;
    int d8 = (j & 15) * 8;
    *(us8*)&Ms[e * 136 + d8] =
        *(const us8*)&PMb[((size_t)(b * 128 + ecol0 + e) * 32 + c) * 128 + d8];
  }
  if (tid < 128) Ns[tid] = PN[(size_t)(b * 32 + c) * 128 + tid];
  // ---- Vt: us2 row-pair stores, conflict-free ----
#pragma unroll
  for (int i = 0; i < 4; i++) {
    us2 w2 = {f2bf(va[i]), f2bf(vb[i])};
    *(us2*)&Vt[(ve4 + i) * 72 + vs0] = w2;
  }
  __syncthreads();

  // ---- P = Q.K^T (wave = row-tile tr=wv; tc 0..3, causal) ----
  {
    const int tr = wv;
    for (int tc = 0; tc < 4; tc++) {  // wave-uniform bound
      f4v acc = {0.f, 0.f, 0.f, 0.f};
      if (tc <= tr) {
#pragma unroll
        for (int ks = 0; ks < 4; ks++) {
          s8v a = *(const s8v*)&Qs[(tr * 16 + ln) * 136 + ks * 32 + q * 8];
          s8v bb = *(const s8v*)&Ks[(tc * 16 + ln) * 136 + ks * 32 + q * 8];
          acc = __builtin_amdgcn_mfma_f32_16x16x32_bf16(a, bb, acc, 0, 0, 0);
        }
      }
      const int s_g = tc * 16 + ln;
#pragma unroll
      for (int r = 0; r < 4; r++) {
        int t_g = tr * 16 + q * 4 + r;
        Ps[t_g * 72 + s_g] = f2bf(s_g <= t_g ? acc[r] : 0.f);
      }
    }
  }
  __syncthreads();

  // ---- denominators: rs[t] = rowsum(P) + Q[t,:].PN ----
  {
    const int t = tid >> 2;
    const int p4 = tid & 3;
    float rsl = 0.f;
#pragma unroll
    for (int s = p4; s < 64; s += 4) rsl += bf2f(Ps[t * 72 + s]);
#pragma unroll
    for (int d = p4; d < 128; d += 4) rsl += bf2f(Qs[t * 136 + d]) * Ns[d];
    rsl += __shfl_down(rsl, 2, 4);
    rsl += __shfl_down(rsl, 1, 4);
    if (p4 == 0) rs[t] = rsl;
  }

  // ---- out = P@V + Q@M (wave: et = wv&1; tr in {wv>>1, wv>>1 + 2}) ----
  const int et = wv & 1;
  f4v acc2[2];
#pragma unroll
  for (int i = 0; i < 2; i++) acc2[i] = (f4v){0.f, 0.f, 0.f, 0.f};
#pragma unroll
  for (int i = 0; i < 2; i++) {
    const int tr2 = (wv >> 1) + 2 * i;
#pragma unroll
    for (int ks2 = 0; ks2 < 2; ks2++) {
      s8v a_p = *(const s8v*)&Ps[(tr2 * 16 + ln) * 72 + ks2 * 32 + q * 8];
      s8v b_v = *(const s8v*)&Vt[(et * 16 + ln) * 72 + ks2 * 32 + q * 8];
      acc2[i] = __builtin_amdgcn_mfma_f32_16x16x32_bf16(a_p, b_v, acc2[i], 0, 0, 0);
    }
#pragma unroll
    for (int ks = 0; ks < 4; ks++) {
      s8v a_q = *(const s8v*)&Qs[(tr2 * 16 + ln) * 136 + ks * 32 + q * 8];
      s8v b_m = *(const s8v*)&Ms[(et * 16 + ln) * 136 + ks * 32 + q * 8];
      acc2[i] = __builtin_amdgcn_mfma_f32_16x16x32_bf16(a_q, b_m, acc2[i], 0, 0, 0);
    }
  }
  __syncthreads();  // rs ready

  // ---- epilogue ----
#pragma unroll
  for (int i = 0; i < 2; i++) {
    const int tr2 = (wv >> 1) + 2 * i;
#pragma unroll
    for (int r = 0; r < 4; r++) {
      int t_g = tr2 * 16 + q * 4 + r;
      float rv = rs[t_g];
      float den = rv + (rv > 0.f ? 1e-6f : (rv < 0.f ? -1e-6f : 0.f));
      out[(size_t)(srow0 + t_g) * 128 + ecol0 + et * 16 + ln] =
          acc2[i][r] / den;
    }
  }
}

// ---------------------------------------------------------------------------
extern "C" void kernel_launch(void* const* d_in, const int* in_sizes, int n_in,
                              void* d_out, int out_size, void* d_ws,
                              size_t ws_size, hipStream_t stream) {
  (void)in_sizes; (void)n_in; (void)out_size; (void)ws_size;
  const float* K = (const float*)d_in[0];
  const float* Q = (const float*)d_in[1];
  const float* V = (const float*)d_in[2];
  const float* W = (const float*)d_in[6];
  float* out = (float*)d_out;
  float* ws = (float*)d_ws;

  u16* phiKb = (u16*)(ws + OFF_PHIKB);
  u16* phiQb = (u16*)(ws + OFF_PHIQB);
  u16* KVTb = (u16*)(ws + OFF_KVTB);
  u16* PMb = (u16*)(ws + OFF_PMB);
  float* N32 = ws + OFF_N32;
  float* PN = ws + OFF_PN;

  phikv_kernel<<<dim3(128, 2), 512, 0, stream>>>(K, Q, V, W, phiKb, phiQb,
                                                 KVTb, N32);
  prefix_kernel<<<65, 256, 0, stream>>>(KVTb, N32, PMb, PN);
  out_kernel<<<512, 256, 0, stream>>>(phiKb, phiQb, V, PMb, PN, out);
}

// Round 10
// 93.498 us; speedup vs baseline: 1.1098x; 1.0041x over previous
//
#include <hip/hip_runtime.h>

// Performer causal linear attention — 2-dispatch bf16-MFMA pipeline, L=64.
// B=4, S=2048, D=128; chunks of L=64 (128 chunks, 32/batch).
//  phikv (256 blk x 512 thr): phi = scale*exp(W@x) via MFMA; K-blocks also
//         emit per-chunk KVT[e][d] (bf16, [b][e][c][d]) + N[d] (fp32).
//  out (512 blk = c x (b,h), 2 blk/CU): in-block exclusive M/N prefix
//         (XCD-swizzled so same-(b,h) blocks share L2; batch-8 pipelined
//         loads — fixes R8's +14us naive scan), then P=QK^T (masked);
//         out = P@V + Q@M ; fp32 denominators.
// (R5: grid barriers ~100us across non-coherent XCD L2s.  R8: naive
//  in-block prefix = latency-serial scan tail.  This round fixes R8.)
typedef float v4 __attribute__((ext_vector_type(4)));
typedef short s8v __attribute__((ext_vector_type(8)));   // bf16x8 fragment
typedef float f4v __attribute__((ext_vector_type(4)));   // mfma C/D
typedef unsigned short u16;
typedef u16 us2 __attribute__((ext_vector_type(2)));
typedef u16 us4 __attribute__((ext_vector_type(4)));
typedef u16 us8 __attribute__((ext_vector_type(8)));

// workspace layout (float units)
#define OFF_PHIKB 0            // bf16 [8192][128]          (524288 f)
#define OFF_PHIQB 524288       // bf16 [8192][128]          (524288 f)
#define OFF_KVTB  1048576      // bf16 [4][128][32][128]    (1048576 f)
#define OFF_N32   2097152      // fp32 [4][32][128]         (16384 f)
// total 2113536 floats = 8.5 MB

__device__ inline u16 f2bf(float f) {
  union { float f; unsigned u; } v; v.f = f;
  unsigned r = v.u + 0x7fffu + ((v.u >> 16) & 1u);
  return (u16)(r >> 16);
}
__device__ inline float bf2f(u16 h) {
  union { unsigned u; float f; } v; v.u = ((unsigned)h) << 16; return v.f;
}

// ---------------------------------------------------------------------------
// Kernel 1: fused phi (+ per-chunk KV/N for the K tensor).  L=64 chunk/block.
// Grid (128, 2): x = 64-row slab (=1 chunk), y = 0:K(+kv) / 1:Q.  512 thr.
// (unchanged from round 9)
// ---------------------------------------------------------------------------
__global__ __launch_bounds__(512) void phikv_kernel(
    const float* __restrict__ K, const float* __restrict__ Q,
    const float* __restrict__ V, const float* __restrict__ W,
    u16* __restrict__ phiKb, u16* __restrict__ phiQb,
    u16* __restrict__ KVTb, float* __restrict__ N32) {
  // phase A: Xb[64][136] @ 0, Wb[128][136] @ 8704   (u16 units)
  // phase B: Pb[64][136] @ 0, KdT[128][72] @ 8704, Vt[128][72] @ 17920
  __shared__ __align__(16) u16 smem[27136];
  __shared__ float srowsq[64];
  __shared__ float scl[64];
  u16* Xb = smem;
  u16* Wb = smem + 8704;
  u16* Pb = smem;
  u16* KdT = smem + 8704;
  u16* Vt = smem + 17920;

  const int tid = threadIdx.x;
  const bool isK = (blockIdx.y == 0);
  const float* X = isK ? K : Q;
  u16* outPhi = isK ? phiKb : phiQb;
  const int row0 = blockIdx.x * 64;
  const int wv = tid >> 6;   // 0..7
  const int lane = tid & 63;
  const int q = lane >> 4;
  const int ln = lane & 15;

  // ---- prefetch V row-pairs (K-blocks): enables conflict-free transpose ----
  v4 vpa[2], vpb[2];
  if (isK) {
#pragma unroll
    for (int k = 0; k < 2; k++) {
      int j = tid + k * 512;
      int s0 = (j & 31) * 2;
      int e4 = (j >> 5) * 4;  // 0..124
      vpa[k] = *(const v4*)&V[(size_t)(row0 + s0) * 128 + e4];
      vpb[k] = *(const v4*)&V[(size_t)(row0 + s0 + 1) * 128 + e4];
    }
  }

  // ---- stage X -> bf16 Xb + per-row sumsq (fp32, shuffle-reduced) ----
#pragma unroll
  for (int k = 0; k < 4; k++) {
    int j = tid + k * 512;
    int r = j >> 5;
    int c4 = (j & 31) * 4;
    v4 x = *(const v4*)&X[(size_t)(row0 + r) * 128 + c4];
    us4 xb;
    float p = 0.f;
#pragma unroll
    for (int i = 0; i < 4; i++) { xb[i] = f2bf(x[i]); p += x[i] * x[i]; }
    *(us4*)&Xb[r * 136 + c4] = xb;
    p += __shfl_down(p, 16, 32);
    p += __shfl_down(p, 8, 32);
    p += __shfl_down(p, 4, 32);
    p += __shfl_down(p, 2, 32);
    p += __shfl_down(p, 1, 32);
    if ((tid & 31) == 0) srowsq[r] = p;
  }
  // ---- stage W -> bf16 Wb ----
#pragma unroll
  for (int k = 0; k < 8; k++) {
    int j = tid + k * 512;
    int r = j >> 5;
    int c4 = (j & 31) * 4;
    v4 w = *(const v4*)&W[(size_t)r * 128 + c4];
    us4 wb;
#pragma unroll
    for (int i = 0; i < 4; i++) wb[i] = f2bf(w[i]);
    *(us4*)&Wb[r * 136 + c4] = wb;
  }
  __syncthreads();
  if (tid < 64)
    scl[tid] = 0.08838834764831845f * __expf(-0.5f * sqrtf(srowsq[tid]));

  // ---- phi MFMA: wave -> row-tile tr=wv>>1, col-tiles (wv&1)*4.. ----
  const int tr = wv >> 1;
  const int cb = (wv & 1) * 4;
  f4v acc[4];
#pragma unroll
  for (int i = 0; i < 4; i++) acc[i] = (f4v){0.f, 0.f, 0.f, 0.f};
#pragma unroll
  for (int ks = 0; ks < 4; ks++) {
    s8v a = *(const s8v*)&Xb[(tr * 16 + ln) * 136 + ks * 32 + q * 8];
#pragma unroll
    for (int i = 0; i < 4; i++) {
      s8v bb = *(const s8v*)&Wb[((cb + i) * 16 + ln) * 136 + ks * 32 + q * 8];
      acc[i] = __builtin_amdgcn_mfma_f32_16x16x32_bf16(a, bb, acc[i], 0, 0, 0);
    }
  }
  __syncthreads();  // Xb/Wb reads done; scl ready

  // ---- epilogue: phi -> Pb (row-major) + KdT (transposed, K-blocks) ----
#pragma unroll
  for (int i = 0; i < 4; i++) {
    const int ct = cb + i;
    us4 col;
#pragma unroll
    for (int r = 0; r < 4; r++) {
      int row = tr * 16 + q * 4 + r;
      u16 hv = f2bf(scl[row] * __expf(acc[i][r]));
      Pb[row * 136 + ct * 16 + ln] = hv;
      col[r] = hv;
    }
    if (isK) *(us4*)&KdT[(ct * 16 + ln) * 72 + tr * 16 + q * 4] = col;
  }
  // ---- Vt from prefetch regs: us2 row-pair stores, conflict-free ----
  if (isK) {
#pragma unroll
    for (int k = 0; k < 2; k++) {
      int j = tid + k * 512;
      int s0 = (j & 31) * 2;
      int e4 = (j >> 5) * 4;
#pragma unroll
      for (int i = 0; i < 4; i++) {
        us2 w2 = {f2bf(vpa[k][i]), f2bf(vpb[k][i])};
        *(us2*)&Vt[(e4 + i) * 72 + s0] = w2;
      }
    }
  }
  __syncthreads();

  // ---- phi -> global (coalesced us8) ----
#pragma unroll
  for (int k = 0; k < 2; k++) {
    int j = tid + k * 512;
    int r = j >> 4;
    int d8 = (j & 15) * 8;
    *(us8*)&outPhi[(size_t)(row0 + r) * 128 + d8] = *(const us8*)&Pb[r * 136 + d8];
  }
  if (!isK) return;

  const int b = row0 >> 11;
  const int c = (row0 >> 6) & 31;  // this block's chunk

  // ---- N sums over 64 rows ----
  if (tid < 128) {
    float ns = 0.f;
#pragma unroll
    for (int s = 0; s < 64; s++) ns += bf2f(KdT[tid * 72 + s]);
    N32[(size_t)(b * 32 + c) * 128 + tid] = ns;
  }

  // ---- kv MFMA: KVT[e][d] = sum_{s<64} V[s][e]*phiK[s][d] ----
  {
    const int et = wv;  // 8 e-tiles / 8 waves
    s8v a0 = *(const s8v*)&Vt[(et * 16 + ln) * 72 + q * 8];
    s8v a1 = *(const s8v*)&Vt[(et * 16 + ln) * 72 + 32 + q * 8];
    f4v ac[8];
#pragma unroll
    for (int dt = 0; dt < 8; dt++) ac[dt] = (f4v){0.f, 0.f, 0.f, 0.f};
#pragma unroll
    for (int dt = 0; dt < 8; dt++) {
      s8v b0 = *(const s8v*)&KdT[(dt * 16 + ln) * 72 + q * 8];
      ac[dt] = __builtin_amdgcn_mfma_f32_16x16x32_bf16(a0, b0, ac[dt], 0, 0, 0);
      s8v b1 = *(const s8v*)&KdT[(dt * 16 + ln) * 72 + 32 + q * 8];
      ac[dt] = __builtin_amdgcn_mfma_f32_16x16x32_bf16(a1, b1, ac[dt], 0, 0, 0);
    }
#pragma unroll
    for (int dt = 0; dt < 8; dt++)
#pragma unroll
      for (int r = 0; r < 4; r++) {
        int e = et * 16 + q * 4 + r;
        int d = dt * 16 + ln;
        KVTb[((size_t)(b * 128 + e) * 32 + c) * 128 + d] = f2bf(ac[dt][r]);
      }
  }
}

// ---------------------------------------------------------------------------
// Kernel 2: outputs with pipelined in-block M/N prefix.
// Block id = c*16 + (b*4+h): same-(b,h) blocks differ by 16 (≡0 mod 8) ->
// same XCD under round-robin placement -> chunk c+1 hits L2 lines chunk c
// fetched.  Prefix loads batch-8 (16 us8 in flight).  Grid 512, 2 blk/CU.
// ---------------------------------------------------------------------------
__global__ __launch_bounds__(256) void out_kernel(
    const u16* __restrict__ phiKb, const u16* __restrict__ phiQb,
    const float* __restrict__ V, const u16* __restrict__ KVTb,
    const float* __restrict__ N32, float* __restrict__ out) {
  __shared__ __align__(16) u16 Qs[64 * 136];  // [t][d]
  __shared__ __align__(16) u16 Ks[64 * 136];  // [s][d]
  __shared__ __align__(16) u16 Ms[32 * 136];  // M^T prefix rows of quarter
  __shared__ __align__(16) u16 Vt[32 * 72];   // [e][s]
  __shared__ __align__(16) u16 Ps[64 * 72];   // [t][s], masked
  __shared__ float Ns[128];
  __shared__ float rs[64];

  const int tid = threadIdx.x;
  const int id = blockIdx.x;
  const int c = id >> 4;         // chunk 0..31
  const int g = id & 15;         // (b,h) group -> XCD-stable
  const int b = g >> 2;
  const int h = g & 3;
  const int srow0 = b * 2048 + c * 64;
  const int ecol0 = h * 32;
  const int wv = tid >> 6;
  const int lane = tid & 63;
  const int q = lane >> 4;
  const int ln = lane & 15;

  // ---- V prefetch (row-pairs of this 32-col quarter) ----
  const int vs0 = (tid & 31) * 2;
  const int ve4 = (tid >> 5) * 4;  // 0..28
  v4 va = *(const v4*)&V[(size_t)(srow0 + vs0) * 128 + ecol0 + ve4];
  v4 vb = *(const v4*)&V[(size_t)(srow0 + vs0 + 1) * 128 + ecol0 + ve4];

  // ---- stage Qs, Ks (64 x 128 bf16 each) ----
#pragma unroll
  for (int k = 0; k < 4; k++) {
    int j = tid + k * 256;  // 0..1023
    int t = j >> 4;
    int d8 = (j & 15) * 8;
    *(us8*)&Qs[t * 136 + d8] = *(const us8*)&phiQb[(size_t)(srow0 + t) * 128 + d8];
    *(us8*)&Ks[t * 136 + d8] = *(const us8*)&phiKb[(size_t)(srow0 + t) * 128 + d8];
  }

  // ---- exclusive M-prefix over chunks < c (fp32 acc, batch-8 loads) ----
  {
    const int se = tid >> 4;          // 0..15
    const int sd8 = (tid & 15) * 8;
    const u16* src0 =
        &KVTb[((size_t)(b * 128 + ecol0 + se) * 32) * 128 + sd8];
    const u16* src1 =
        &KVTb[((size_t)(b * 128 + ecol0 + 16 + se) * 32) * 128 + sd8];
    float m0[8], m1[8];
#pragma unroll
    for (int i = 0; i < 8; i++) { m0[i] = 0.f; m1[i] = 0.f; }
    for (int base = 0; base < c; base += 8) {
      us8 t0[8], t1[8];
#pragma unroll
      for (int u = 0; u < 8; u++) {
        if (base + u < c) {
          t0[u] = *(const us8*)&src0[(base + u) * 128];
          t1[u] = *(const us8*)&src1[(base + u) * 128];
        }
      }
#pragma unroll
      for (int u = 0; u < 8; u++) {
        if (base + u < c) {
#pragma unroll
          for (int i = 0; i < 8; i++) {
            m0[i] += bf2f(t0[u][i]);
            m1[i] += bf2f(t1[u][i]);
          }
        }
      }
    }
    us8 w0, w1;
#pragma unroll
    for (int i = 0; i < 8; i++) { w0[i] = f2bf(m0[i]); w1[i] = f2bf(m1[i]); }
    *(us8*)&Ms[se * 136 + sd8] = w0;
    *(us8*)&Ms[(16 + se) * 136 + sd8] = w1;
  }
  // ---- exclusive N-prefix (batch-8) ----
  if (tid < 128) {
    float na = 0.f;
    for (int base = 0; base < c; base += 8) {
      float t[8];
#pragma unroll
      for (int u = 0; u < 8; u++)
        t[u] = (base + u < c) ? N32[(size_t)(b * 32 + base + u) * 128 + tid]
                              : 0.f;
#pragma unroll
      for (int u = 0; u < 8; u++) na += t[u];
    }
    Ns[tid] = na;
  }
  // ---- Vt: us2 row-pair stores, conflict-free ----
#pragma unroll
  for (int i = 0; i < 4; i++) {
    us2 w2 = {f2bf(va[i]), f2bf(vb[i])};
    *(us2*)&Vt[(ve4 + i) * 72 + vs0] = w2;
  }
  __syncthreads();

  // ---- P = Q.K^T (wave = row-tile tr=wv; tc 0..3, causal) ----
  {
    const int tr = wv;
    for (int tc = 0; tc < 4; tc++) {  // wave-uniform bound
      f4v acc = {0.f, 0.f, 0.f, 0.f};
      if (tc <= tr) {
#pragma unroll
        for (int ks = 0; ks < 4; ks++) {
          s8v a = *(const s8v*)&Qs[(tr * 16 + ln) * 136 + ks * 32 + q * 8];
          s8v bb = *(const s8v*)&Ks[(tc * 16 + ln) * 136 + ks * 32 + q * 8];
          acc = __builtin_amdgcn_mfma_f32_16x16x32_bf16(a, bb, acc, 0, 0, 0);
        }
      }
      const int s_g = tc * 16 + ln;
#pragma unroll
      for (int r = 0; r < 4; r++) {
        int t_g = tr * 16 + q * 4 + r;
        Ps[t_g * 72 + s_g] = f2bf(s_g <= t_g ? acc[r] : 0.f);
      }
    }
  }
  __syncthreads();

  // ---- denominators: rs[t] = rowsum(P) + Q[t,:].Ns ----
  {
    const int t = tid >> 2;
    const int p4 = tid & 3;
    float rsl = 0.f;
#pragma unroll
    for (int s = p4; s < 64; s += 4) rsl += bf2f(Ps[t * 72 + s]);
#pragma unroll
    for (int d = p4; d < 128; d += 4) rsl += bf2f(Qs[t * 136 + d]) * Ns[d];
    rsl += __shfl_down(rsl, 2, 4);
    rsl += __shfl_down(rsl, 1, 4);
    if (p4 == 0) rs[t] = rsl;
  }

  // ---- out = P@V + Q@M (wave: et = wv&1; tr in {wv>>1, wv>>1 + 2}) ----
  const int et = wv & 1;
  f4v acc2[2];
#pragma unroll
  for (int i = 0; i < 2; i++) acc2[i] = (f4v){0.f, 0.f, 0.f, 0.f};
#pragma unroll
  for (int i = 0; i < 2; i++) {
    const int tr2 = (wv >> 1) + 2 * i;
#pragma unroll
    for (int ks2 = 0; ks2 < 2; ks2++) {
      s8v a_p = *(const s8v*)&Ps[(tr2 * 16 + ln) * 72 + ks2 * 32 + q * 8];
      s8v b_v = *(const s8v*)&Vt[(et * 16 + ln) * 72 + ks2 * 32 + q * 8];
      acc2[i] = __builtin_amdgcn_mfma_f32_16x16x32_bf16(a_p, b_v, acc2[i], 0, 0, 0);
    }
#pragma unroll
    for (int ks = 0; ks < 4; ks++) {
      s8v a_q = *(const s8v*)&Qs[(tr2 * 16 + ln) * 136 + ks * 32 + q * 8];
      s8v b_m = *(const s8v*)&Ms[(et * 16 + ln) * 136 + ks * 32 + q * 8];
      acc2[i] = __builtin_amdgcn_mfma_f32_16x16x32_bf16(a_q, b_m, acc2[i], 0, 0, 0);
    }
  }
  __syncthreads();  // rs ready

  // ---- epilogue ----
#pragma unroll
  for (int i = 0; i < 2; i++) {
    const int tr2 = (wv >> 1) + 2 * i;
#pragma unroll
    for (int r = 0; r < 4; r++) {
      int t_g = tr2 * 16 + q * 4 + r;
      float rv = rs[t_g];
      float den = rv + (rv > 0.f ? 1e-6f : (rv < 0.f ? -1e-6f : 0.f));
      out[(size_t)(srow0 + t_g) * 128 + ecol0 + et * 16 + ln] =
          acc2[i][r] / den;
    }
  }
}

// ---------------------------------------------------------------------------
extern "C" void kernel_launch(void* const* d_in, const int* in_sizes, int n_in,
                              void* d_out, int out_size, void* d_ws,
                              size_t ws_size, hipStream_t stream) {
  (void)in_sizes; (void)n_in; (void)out_size; (void)ws_size;
  const float* K = (const float*)d_in[0];
  const float* Q = (const float*)d_in[1];
  const float* V = (const float*)d_in[2];
  const float* W = (const float*)d_in[6];
  float* out = (float*)d_out;
  float* ws = (float*)d_ws;

  u16* phiKb = (u16*)(ws + OFF_PHIKB);
  u16* phiQb = (u16*)(ws + OFF_PHIQB);
  u16* KVTb = (u16*)(ws + OFF_KVTB);
  float* N32 = ws + OFF_N32;

  phikv_kernel<<<dim3(128, 2), 512, 0, stream>>>(K, Q, V, W, phiKb, phiQb,
                                                 KVTb, N32);
  out_kernel<<<512, 256, 0, stream>>>(phiKb, phiQb, V, KVTb, N32, out);
}